// Round 1
// baseline (82.432 us; speedup 1.0000x reference)
//
#include <hip/hip_runtime.h>

#define N_KPS 1024
#define N_PTS 120000
#define BLOCK 512                  // 8 waves per block
#define KSPLIT 8                   // one wave per K-chunk
#define KCHUNK (N_KPS / KSPLIT)    // 128 control points per wave
#define PTS_PER_BLOCK 128          // 64 lanes x 2 points/thread
#define CHUNK 8                    // ctrl points per pipelined chunk
#define NCHUNK (KCHUNK / CHUNK)    // 16

typedef float v2f __attribute__((ext_vector_type(2)));

// r3 post-mortem: k0 = f(threadIdx.x>>6) is divergent to LLVM -> kps/W reads
// became per-lane vector loads; ~200cyc vmcnt waits with ~2 waves/SIMD = 49%
// stall. Fixes: (a) readfirstlane forces the wave id into an SGPR so control
// data loads are s_load_dwordx4 (scalar, no per-lane latency); (b) explicit
// next-chunk prefetch so each s_waitcnt lands after a ~160-cycle compute body;
// (c) 8 waves/block x 938 blocks = 7.3 waves/SIMD for real latency hiding.
// r5 (this round): tail epilogue split across waves 0 and 1 (was wave 0 only);
// rest unchanged — this run re-captures baseline counters after infra failure.
__global__ __launch_bounds__(BLOCK) void tps_warp_kernel(
    const float2* __restrict__ pts,
    const float*  __restrict__ kps,
    const float*  __restrict__ W,
    float2*       __restrict__ out)
{
    __shared__ float4 part[KSPLIT][64];

    const int lane = threadIdx.x & 63;
    // Provably wave-uniform wave id -> SGPR -> scalar loads for kps/W.
    const int wv = __builtin_amdgcn_readfirstlane(threadIdx.x) >> 6;

    const int base = blockIdx.x * PTS_PER_BLOCK;
    const int j0 = base + lane;
    const int j1 = base + 64 + lane;
    const int j0c = j0 < N_PTS ? j0 : N_PTS - 1;
    const int j1c = j1 < N_PTS ? j1 : N_PTS - 1;
    const float2 p0 = pts[j0c];
    const float2 p1 = pts[j1c];

    v2f px = {p0.x, p1.x};
    v2f py = {p0.y, p1.y};
    v2f zx = {0.0f, 0.0f};
    v2f zy = {0.0f, 0.0f};
    const v2f tiny = {1e-37f, 1e-37f};

    auto eval = [&](float kx, float ky, float wx, float wy) {
        v2f dx = v2f{kx, kx} - px;
        v2f dy = v2f{ky, ky} - py;
        v2f d2 = __builtin_elementwise_fma(dy, dy, dx * dx);
        // d2==0 -> clamp: v = 1e-37*log2(1e-37) ~ 0, matching reference's
        // where(l2==0, 1.0) -> 0.5*1*ln(1) = 0.
        d2 = __builtin_elementwise_max(d2, tiny);
        v2f t;
        t.x = __log2f(d2.x);
        t.y = __log2f(d2.y);
        v2f v = d2 * t;                      // 0.5*ln2 folded in at the end
        zx = __builtin_elementwise_fma(v, v2f{wx, wx}, zx);
        zy = __builtin_elementwise_fma(v, v2f{wy, wy}, zy);
    };

    // Control data as float4 pairs: kp4[t] = {kx,ky,kx,ky}, wp4[t] = {wx,wy,wx,wy}.
    const float4* __restrict__ kp4 = (const float4*)kps;   // 512 entries
    const float4* __restrict__ wp4 = (const float4*)W;
    const int cbase = wv * (KCHUNK / 2);                   // float4 index base

    // Prime chunk 0.
    float4 kc[4], wc[4];
    #pragma unroll
    for (int t = 0; t < 4; ++t) {
        kc[t] = kp4[cbase + t];
        wc[t] = wp4[cbase + t];
    }

    for (int c = 0; c < NCHUNK; ++c) {
        // Prefetch next chunk (clamped re-read on the last iteration — K$ hit).
        const int nc = (c + 1 < NCHUNK) ? c + 1 : c;
        float4 kn[4], wn[4];
        #pragma unroll
        for (int t = 0; t < 4; ++t) {
            kn[t] = kp4[cbase + nc * 4 + t];
            wn[t] = wp4[cbase + nc * 4 + t];
        }
        // Compute current chunk: 8 ctrl pts x 2 packed points = 16 logs in flight.
        #pragma unroll
        for (int t = 0; t < 4; ++t) {
            eval(kc[t].x, kc[t].y, wc[t].x, wc[t].y);
            eval(kc[t].z, kc[t].w, wc[t].z, wc[t].w);
        }
        #pragma unroll
        for (int t = 0; t < 4; ++t) {
            kc[t] = kn[t];
            wc[t] = wn[t];
        }
    }

    part[wv][lane] = make_float4(zx.x, zy.x, zx.y, zy.y);
    __syncthreads();

    // Tail split: wave 0 finalizes point set j0 (.x/.y partials), wave 1
    // finalizes j1 (.z/.w). Wave-uniform select -> no divergence; halves the
    // serial epilogue vs the old wave-0-only version.
    if (wv < 2) {
        const bool hi = (wv == 1);
        const float2 p = hi ? p1 : p0;
        const int j = hi ? j1 : j0;

        float sx = 0.f, sy = 0.f;
        #pragma unroll
        for (int w = 0; w < KSPLIT; w += 2) {   // pairwise-ish tree
            float4 a = part[w][lane];
            float4 b = part[w + 1][lane];
            sx += (hi ? a.z : a.x) + (hi ? b.z : b.x);
            sy += (hi ? a.w : a.y) + (hi ? b.w : b.y);
        }

        const float scale = 0.34657359027997264f;  // 0.5 * ln(2)
        float w1x = W[2048], w1y = W[2049];
        float wxx = W[2050], wxy = W[2051];
        float wyx = W[2052], wyy = W[2053];

        if (j < N_PTS) {
            float ox = p.x + fmaf(scale, sx, fmaf(wxx, p.x, fmaf(wyx, p.y, w1x)));
            float oy = p.y + fmaf(scale, sy, fmaf(wxy, p.x, fmaf(wyy, p.y, w1y)));
            out[j] = make_float2(ox, oy);
        }
    }
}

extern "C" void kernel_launch(void* const* d_in, const int* in_sizes, int n_in,
                              void* d_out, int out_size, void* d_ws, size_t ws_size,
                              hipStream_t stream) {
    const float* pts = (const float*)d_in[0];   // [120000, 2]
    const float* kps = (const float*)d_in[1];   // [1024, 2]
    const float* W   = (const float*)d_in[2];   // [1027, 2]
    float* out = (float*)d_out;                 // [120000, 2]

    const int grid = (N_PTS + PTS_PER_BLOCK - 1) / PTS_PER_BLOCK;  // 938
    tps_warp_kernel<<<grid, BLOCK, 0, stream>>>(
        (const float2*)pts, kps, W, (float2*)out);
}

// Round 2
// 78.316 us; speedup vs baseline: 1.0526x; 1.0526x over previous
//
#include <hip/hip_runtime.h>

#define N_KPS 1024
#define N_PTS 120000
#define BLOCK 512                  // 8 waves per block
#define KSPLIT 8                   // one wave per K-chunk
#define KCHUNK (N_KPS / KSPLIT)    // 128 control points per wave
#define PTS_PER_BLOCK 128          // 64 lanes x 2 points/thread
#define CHUNK 8                    // ctrl points per pipelined chunk
#define NCHUNK (KCHUNK / CHUNK)    // 16

typedef float v2f __attribute__((ext_vector_type(2)));

// r3: readfirstlane wave id -> SGPR -> kps/W become s_load_dwordx4 (scalar).
// r5: epilogue split across waves 0/1. Neutral (82.5 -> 82.43) => tail is
//     negligible, as modeled.
// r6 (this round): theory = kernel half (~42us of the 82) is ISSUE-bound, not
// stall-bound (7.3 waves/SIMD resident; ~29k VALU cyc + ~16-33k trans cyc +
// ~5k scalar-pipe cyc per SIMD). Changes:
//   (a) epsilon folded into the fma chain: d2 = fma(dy,dy,fma(dx,dx,1e-37))
//       -> v_max eliminated (arg to log provably >= 1e-37; d2==0 case gives
//       1e-37*log2(1e-37) ~ -1e-35 ~ 0, matching reference where(l2==0,1)).
//   (b) NCHUNK loop fully unrolled: 16x{16 s_mov prefetch-copies + branch}
//       become SSA renames (scalar ALU is shared per-CU by 4 SIMDs — this
//       was real issue pressure); s_loads schedule chunks ahead.
// Prediction: dur_us 82.4 -> ~74-77 if issue-bound; unchanged => pivot.
__global__ __launch_bounds__(BLOCK) void tps_warp_kernel(
    const float2* __restrict__ pts,
    const float*  __restrict__ kps,
    const float*  __restrict__ W,
    float2*       __restrict__ out)
{
    __shared__ float4 part[KSPLIT][64];

    const int lane = threadIdx.x & 63;
    // Provably wave-uniform wave id -> SGPR -> scalar loads for kps/W.
    const int wv = __builtin_amdgcn_readfirstlane(threadIdx.x) >> 6;

    const int base = blockIdx.x * PTS_PER_BLOCK;
    const int j0 = base + lane;
    const int j1 = base + 64 + lane;
    const int j0c = j0 < N_PTS ? j0 : N_PTS - 1;
    const int j1c = j1 < N_PTS ? j1 : N_PTS - 1;
    const float2 p0 = pts[j0c];
    const float2 p1 = pts[j1c];

    v2f px = {p0.x, p1.x};
    v2f py = {p0.y, p1.y};
    v2f zx = {0.0f, 0.0f};
    v2f zy = {0.0f, 0.0f};
    const v2f tiny = {1e-37f, 1e-37f};

    auto eval = [&](float kx, float ky, float wx, float wy) {
        v2f dx = v2f{kx, kx} - px;
        v2f dy = v2f{ky, ky} - py;
        // Epsilon folded into the chain: d2 >= 1e-37 always, no v_max needed.
        v2f d2 = __builtin_elementwise_fma(
            dy, dy, __builtin_elementwise_fma(dx, dx, tiny));
        v2f t;
        t.x = __log2f(d2.x);
        t.y = __log2f(d2.y);
        v2f v = d2 * t;                      // 0.5*ln2 folded in at the end
        zx = __builtin_elementwise_fma(v, v2f{wx, wx}, zx);
        zy = __builtin_elementwise_fma(v, v2f{wy, wy}, zy);
    };

    // Control data as float4 pairs: kp4[t] = {kx,ky,kx,ky}, wp4[t] = {wx,wy,wx,wy}.
    const float4* __restrict__ kp4 = (const float4*)kps;   // 512 entries
    const float4* __restrict__ wp4 = (const float4*)W;
    const int cbase = wv * (KCHUNK / 2);                   // float4 index base

    // Fully unrolled: prefetch copies become SSA renames; s_loads schedule
    // ahead under compiler control. ~1.8k instr body, fits I$.
    #pragma unroll
    for (int c = 0; c < NCHUNK; ++c) {
        float4 kc[4], wc[4];
        #pragma unroll
        for (int t = 0; t < 4; ++t) {
            kc[t] = kp4[cbase + c * 4 + t];
            wc[t] = wp4[cbase + c * 4 + t];
        }
        #pragma unroll
        for (int t = 0; t < 4; ++t) {
            eval(kc[t].x, kc[t].y, wc[t].x, wc[t].y);
            eval(kc[t].z, kc[t].w, wc[t].z, wc[t].w);
        }
    }

    part[wv][lane] = make_float4(zx.x, zy.x, zx.y, zy.y);
    __syncthreads();

    // Tail split: wave 0 finalizes j0 (.x/.y partials), wave 1 finalizes j1
    // (.z/.w). Wave-uniform select -> no divergence.
    if (wv < 2) {
        const bool hi = (wv == 1);
        const float2 p = hi ? p1 : p0;
        const int j = hi ? j1 : j0;

        float sx = 0.f, sy = 0.f;
        #pragma unroll
        for (int w = 0; w < KSPLIT; w += 2) {
            float4 a = part[w][lane];
            float4 b = part[w + 1][lane];
            sx += (hi ? a.z : a.x) + (hi ? b.z : b.x);
            sy += (hi ? a.w : a.y) + (hi ? b.w : b.y);
        }

        const float scale = 0.34657359027997264f;  // 0.5 * ln(2)
        float w1x = W[2048], w1y = W[2049];
        float wxx = W[2050], wxy = W[2051];
        float wyx = W[2052], wyy = W[2053];

        if (j < N_PTS) {
            float ox = p.x + fmaf(scale, sx, fmaf(wxx, p.x, fmaf(wyx, p.y, w1x)));
            float oy = p.y + fmaf(scale, sy, fmaf(wxy, p.x, fmaf(wyy, p.y, w1y)));
            out[j] = make_float2(ox, oy);
        }
    }
}

extern "C" void kernel_launch(void* const* d_in, const int* in_sizes, int n_in,
                              void* d_out, int out_size, void* d_ws, size_t ws_size,
                              hipStream_t stream) {
    const float* pts = (const float*)d_in[0];   // [120000, 2]
    const float* kps = (const float*)d_in[1];   // [1024, 2]
    const float* W   = (const float*)d_in[2];   // [1027, 2]
    float* out = (float*)d_out;                 // [120000, 2]

    const int grid = (N_PTS + PTS_PER_BLOCK - 1) / PTS_PER_BLOCK;  // 938
    tps_warp_kernel<<<grid, BLOCK, 0, stream>>>(
        (const float2*)pts, kps, W, (float2*)out);
}